// Round 5
// baseline (686.304 us; speedup 1.0000x reference)
//
#include <hip/hip_runtime.h>
#include <hip/hip_fp16.h>

// Problem constants: C=64, S=2048, H=512; rows = C*S = 131072
#define HDIM 512

typedef __fp16 fp16x2 __attribute__((ext_vector_type(2)));
typedef _Float16 h4 __attribute__((ext_vector_type(4)));
typedef _Float16 h8 __attribute__((ext_vector_type(8)));
typedef __attribute__((ext_vector_type(4))) float floatx4;

// raw barrier: LDS-visibility only, no vmem drain (unlike __syncthreads)
__device__ __forceinline__ void lds_barrier() {
  asm volatile("s_waitcnt lgkmcnt(0)\n\ts_barrier" ::: "memory");
}
__device__ __forceinline__ void issue_fence() {  // pin vm-issue order
  asm volatile("" ::: "memory");
}

// ---------------------------------------------------------------------------
// Kernel 1: W fp32 -> fp16 (RTE)
// ---------------------------------------------------------------------------
__global__ __launch_bounds__(256) void prep_w_kernel(
    const float* __restrict__ W, _Float16* __restrict__ wf) {
  int i = (blockIdx.x * 256 + threadIdx.x) * 4;
  float4 f = *(const float4*)(W + i);
  wf[i + 0] = (_Float16)f.x;
  wf[i + 1] = (_Float16)f.y;
  wf[i + 2] = (_Float16)f.z;
  wf[i + 3] = (_Float16)f.w;
}

// ---------------------------------------------------------------------------
// Kernel 2: GEMM, BM=64 x BN=512 (full row), BK=32, 8 waves (1M x 8N),
// 75 KB LDS -> 2 blocks/CU (round-2's 151 KB structure was 1 block/CU and
// convoy-bound at 6000 cyc/K-step). W staging is WAVE-LOCAL: wave w DMAs
// exactly rows [w*64, w*64+64) that only it reads, so W needs no cross-wave
// barrier; the per-step barrier is lgkm-only for the shared x tile. dma_t
// drained by a counted vmcnt (never 0 mid-loop).
// ---------------------------------------------------------------------------
#define XS_H (64 * 40)   // x tile, stride padded 32->40 halves
#define WS_H (512 * 32)  // w tile halves per buffer

__device__ __forceinline__ void issue_w_dma(const _Float16* __restrict__ wf,
                                            _Float16* dst, int kt, int lane,
                                            int widx) {
#pragma unroll
  for (int q = 0; q < 4; ++q) {
    // lane i -> LDS row (widx*64 + q*16 + i>>2), physical chunk i&3.
    // source-side XOR swizzle: stored-at-p holds logical chunk p ^ f(row),
    // f(row) = ((row&15)>>1)&3 = (lane>>3)&3  (row&15 == lane>>2 here).
    int src = (lane & 3) ^ ((lane >> 3) & 3);
    int row = widx * 64 + q * 16 + (lane >> 2);
    size_t goff = (size_t)row * HDIM + kt * 32 + src * 8;
    __builtin_amdgcn_global_load_lds(
        (const __attribute__((address_space(1))) void*)(wf + goff),
        (__attribute__((address_space(3))) void*)(
            dst + (widx * 64 + q * 16) * 32),
        16, 0, 0);
  }
}

__global__ __launch_bounds__(512, 4) void gemm_kernel(
    const float* __restrict__ x, const _Float16* __restrict__ wf,
    const float* __restrict__ bias, __half* __restrict__ e,
    float* __restrict__ u_gemm) {
  __shared__ __align__(16) _Float16 smem[2 * XS_H + 2 * WS_H];  // 75776 B
  _Float16* xs0 = smem;
  _Float16* xs1 = smem + XS_H;
  _Float16* wsm = smem + 2 * XS_H;

  const int tid = threadIdx.x;
  const int lane = tid & 63;
  const int widx = tid >> 6;  // 0..7 == wave_n (cols widx*64..+63)
  const int lrow = lane & 15, quad = lane >> 4;

  const int bid = blockIdx.x;  // 2048 blocks x 64 rows
  const int row0 = bid * 64;

  const int xrow = tid >> 3;  // 0..63
  const int xcg = tid & 7;    // float4 index within 32-float K-slice
  const float* xbase = x + (size_t)(row0 + xrow) * HDIM + xcg * 4;

  floatx4 acc[4][4];
#pragma unroll
  for (int i = 0; i < 4; ++i)
#pragma unroll
    for (int j = 0; j < 4; ++j) acc[i][j] = (floatx4){0.f, 0.f, 0.f, 0.f};

  float4 xr[2];

  // prologue: dma_0 ; x_0 ; x_1   (dma_0 older than x_0 => drained by its wait)
  issue_w_dma(wf, wsm, 0, lane, widx);
  issue_fence();
  xr[0] = *(const float4*)xbase;
  issue_fence();
  xr[1] = *(const float4*)(xbase + 32);
  issue_fence();

  const int chunkB = quad ^ ((lrow >> 1) & 3);  // conflict-minimal read swizzle

#pragma unroll
  for (int t = 0; t < 16; ++t) {
    // ---- stage x_t (fp32->fp16); compiler's wait for x_t drains dma_t here
    {
      float4 a0 = xr[t & 1];
      union { h4 v4; fp16x2 v2[2]; } u;
      u.v2[0] = __builtin_amdgcn_cvt_pkrtz(a0.x, a0.y);
      u.v2[1] = __builtin_amdgcn_cvt_pkrtz(a0.z, a0.w);
      _Float16* xsd = (t & 1) ? xs1 : xs0;
      *(h4*)&xsd[xrow * 40 + xcg * 4] = u.v4;
    }
    lds_barrier();  // xs(t) visible to all waves (lgkm only, no vmem drain)
    // ---- issue next loads (dma first: keeps dma_k older than x_k)
    if (t <= 14) {
      issue_w_dma(wf, wsm + ((t + 1) & 1) * WS_H, t + 1, lane, widx);
      issue_fence();
    }
    if (t <= 13) {
      xr[t & 1] = *(const float4*)(xbase + (t + 2) * 32);
      issue_fence();
    }
    // ---- drain this wave's dma_t (wave-local W => wave-local wait suffices)
    // queue: [dma_t(4), x_{t+1}(1), dma_{t+1}(4), x_{t+2}(1)] -> vmcnt(6)
    if (t >= 1 && t <= 13) asm volatile("s_waitcnt vmcnt(6)" ::: "memory");
    else if (t == 14) asm volatile("s_waitcnt vmcnt(5)" ::: "memory");
    else if (t == 15) asm volatile("s_waitcnt vmcnt(0)" ::: "memory");
    // ---- compute
    const _Float16* xsr = (t & 1) ? xs1 : xs0;
    const _Float16* wcur = wsm + (t & 1) * WS_H;
    h8 a[4], bh[4];
#pragma unroll
    for (int mt = 0; mt < 4; ++mt)
      a[mt] = *(const h8*)&xsr[(mt * 16 + lrow) * 40 + quad * 8];
#pragma unroll
    for (int nt = 0; nt < 4; ++nt)
      bh[nt] = *(const h8*)&wcur[(widx * 64 + nt * 16 + lrow) * 32 +
                                 chunkB * 8];
    __builtin_amdgcn_s_setprio(1);
#pragma unroll
    for (int mt = 0; mt < 4; ++mt)
#pragma unroll
      for (int nt = 0; nt < 4; ++nt)
        acc[mt][nt] = __builtin_amdgcn_mfma_f32_16x16x32_f16(
            a[mt], bh[nt], acc[mt][nt], 0, 0, 0);
    __builtin_amdgcn_s_setprio(0);
  }

  // ---- epilogue: full-row squash + e-write + iteration-1 partial sums ----
  float* sqp = (float*)smem;        // [8][64] (reuses xs0 region; safe: last
  float* scs = (float*)smem + 512;  // [64]    compute reads xs1/wsm only)

  float bias_v[4];
  int coll[4];
#pragma unroll
  for (int nt = 0; nt < 4; ++nt) {
    coll[nt] = widx * 64 + nt * 16 + lrow;
    bias_v[nt] = bias[coll[nt]];
  }
#pragma unroll
  for (int mt = 0; mt < 4; ++mt) {
#pragma unroll
    for (int r = 0; r < 4; ++r) {
      float s = 0.f;
#pragma unroll
      for (int nt = 0; nt < 4; ++nt) {
        float yv = acc[mt][nt][r] + bias_v[nt];
        s += yv * yv;
      }
      s += __shfl_xor(s, 1, 64);
      s += __shfl_xor(s, 2, 64);
      s += __shfl_xor(s, 4, 64);
      s += __shfl_xor(s, 8, 64);
      if (lrow == 0) sqp[widx * 64 + mt * 16 + quad * 4 + r] = s;
    }
  }
  lds_barrier();
  if (tid < 64) {
    float s = 0.f;
#pragma unroll
    for (int w = 0; w < 8; ++w) s += sqp[w * 64 + tid];
    scs[tid] = s / ((1.f + s) * sqrtf(s + 1e-7f));
  }
  lds_barrier();

  float up[4] = {0.f, 0.f, 0.f, 0.f};
#pragma unroll
  for (int mt = 0; mt < 4; ++mt) {
#pragma unroll
    for (int r = 0; r < 4; ++r) {
      int rowl = mt * 16 + quad * 4 + r;
      float scv = scs[rowl];
      __half* erow = e + (size_t)(row0 + rowl) * HDIM;
#pragma unroll
      for (int nt = 0; nt < 4; ++nt) {
        float ev = (acc[mt][nt][r] + bias_v[nt]) * scv;
        erow[coll[nt]] = __float2half(ev);
        up[nt] += ev;
      }
    }
  }
  // col-sums of e over this block's 64 rows -> u_gemm[cap][chunk][col]
#pragma unroll
  for (int nt = 0; nt < 4; ++nt) {
    float v = up[nt];
    v += __shfl_xor(v, 16, 64);
    v += __shfl_xor(v, 32, 64);
    if (quad == 0)
      u_gemm[(size_t)(bid >> 5) * 32 * HDIM + (size_t)(bid & 31) * HDIM +
             coll[nt]] = v;
  }
}

// ---------------------------------------------------------------------------
// Kernel 3: one routing iteration, sync via kernel boundaries only.
// 2048 blocks x 256 (64 rows/block, 16 rows/wave) at launch_bounds(256,6)
// -> ~24 waves/CU (round-4 ran 16). Phase R: every block redundantly
// computes c for its capsule from 32 partials (L2-resident). Phase B:
// stream e rows, update b, emit 32-chunk partials.
// ---------------------------------------------------------------------------
template <bool FIRST>
__global__ __launch_bounds__(256, 6) void route_iter_kernel(
    const __half* __restrict__ e, const float* __restrict__ u_in,
    const float* __restrict__ den_in, float* __restrict__ b,
    float* __restrict__ u_out, float* __restrict__ den_out) {
  const int tid = threadIdx.x;
  const int w = tid >> 6;
  const int lane = tid & 63;
  const int bid = blockIdx.x;
  const int cap = bid >> 5;  // 32 blocks per capsule
  const int r0 = bid * 64;

  __shared__ float csh[512];
  __shared__ float red[256];
  __shared__ float lred[4][512];
  __shared__ float ldn[4];
  __shared__ float sden;

  // ---- phase R: c = squash(sum u / den) for this block's capsule ----
  float v0 = 0.f, v1 = 0.f;
  {
    const float* upb = u_in + (size_t)cap * 32 * HDIM;
#pragma unroll
    for (int ch = 0; ch < 32; ++ch) {
      v0 += upb[ch * HDIM + tid];
      v1 += upb[ch * HDIM + tid + 256];
    }
  }
  float den;
  if (FIRST) {
    den = 2048.f;  // sum of exp(0) over S, exactly
  } else {
    red[tid] = (tid < 32) ? den_in[cap * 32 + tid] : 0.f;
    __syncthreads();
    if (tid == 0) {
      float s = 0.f;
#pragma unroll
      for (int i = 0; i < 32; ++i) s += red[i];
      sden = s;
    }
    __syncthreads();
    den = sden;
    __syncthreads();
  }
  v0 /= den;
  v1 /= den;
  red[tid] = v0 * v0 + v1 * v1;
  __syncthreads();
  for (int s = 128; s > 0; s >>= 1) {
    if (tid < s) red[tid] += red[tid + s];
    __syncthreads();
  }
  const float sqv = red[0];
  const float scv = sqv / ((1.f + sqv) * sqrtf(sqv + 1e-7f));
  csh[tid] = v0 * scv;
  csh[tid + 256] = v1 * scv;
  __syncthreads();

  // ---- phase B: b += e.c ; partial softmax-weighted sums ----
  float c8[8];
#pragma unroll
  for (int k = 0; k < 8; ++k) c8[k] = csh[lane * 8 + k];
  float u8[8] = {0, 0, 0, 0, 0, 0, 0, 0};
  float den_w = 0.f;

  union U { int4 v; __half hh[8]; };
  U cur[4], nxt[4];
  const __half* yb = e + (size_t)(r0 + w * 16) * HDIM + lane * 8;
#pragma unroll
  for (int j = 0; j < 4; ++j) cur[j].v = *(const int4*)(yb + (size_t)j * HDIM);

  for (int g = 0; g < 4; ++g) {
    if (g < 3) {
#pragma unroll
      for (int j = 0; j < 4; ++j)
        nxt[j].v = *(const int4*)(yb + (size_t)(g * 4 + 4 + j) * HDIM);
    }
    float dot[4];
#pragma unroll
    for (int j = 0; j < 4; ++j) {
      float d = 0.f;
#pragma unroll
      for (int k = 0; k < 8; ++k) d += __half2float(cur[j].hh[k]) * c8[k];
      dot[j] = d;
    }
#pragma unroll
    for (int s = 1; s < 64; s <<= 1) {
#pragma unroll
      for (int j = 0; j < 4; ++j) dot[j] += __shfl_xor(dot[j], s, 64);
    }
#pragma unroll
    for (int j = 0; j < 4; ++j) {
      const int rl = w * 16 + g * 4 + j;  // row within block
      float bn = FIRST ? dot[j] : (b[r0 + rl] + dot[j]);
      if (FIRST && lane == 0) b[r0 + rl] = bn;  // launch-2 write is dead
      float wj = __expf(bn);  // |b| small: no max-subtraction needed
      den_w += wj;
#pragma unroll
      for (int k = 0; k < 8; ++k) u8[k] += wj * __half2float(cur[j].hh[k]);
    }
#pragma unroll
    for (int j = 0; j < 4; ++j) cur[j] = nxt[j];
  }

  // intra-block reduction: 4 waves -> one partial per block
#pragma unroll
  for (int k = 0; k < 8; ++k) lred[w][lane * 8 + k] = u8[k];
  if (lane == 0) ldn[w] = den_w;
  __syncthreads();
  float* ur = u_out + (size_t)cap * 32 * HDIM + (size_t)(bid & 31) * HDIM;
#pragma unroll
  for (int hh = 0; hh < 2; ++hh) {
    int h = hh * 256 + tid;
    ur[h] = lred[0][h] + lred[1][h] + lred[2][h] + lred[3][h];
  }
  if (tid == 0)
    den_out[cap * 32 + (bid & 31)] = ldn[0] + ldn[1] + ldn[2] + ldn[3];
}

// ---------------------------------------------------------------------------
// Kernel 4: final phase R only: c3 = squash(sum u / sum den) -> out
// ---------------------------------------------------------------------------
__global__ __launch_bounds__(512) void route_final_kernel(
    const float* __restrict__ u_in, const float* __restrict__ den_in,
    float* __restrict__ out) {
  const int cap = blockIdx.x;
  const int t = threadIdx.x;
  __shared__ float red[512];
  __shared__ float sden;

  red[t] = (t < 32) ? den_in[cap * 32 + t] : 0.f;
  __syncthreads();
  if (t == 0) {
    float s = 0.f;
#pragma unroll
    for (int i = 0; i < 32; ++i) s += red[i];
    sden = s;
  }
  __syncthreads();
  const float den = sden;

  float v = 0.f;
  const float* up = u_in + (size_t)cap * 32 * HDIM + t;
#pragma unroll
  for (int ch = 0; ch < 32; ++ch) v += up[ch * HDIM];
  v /= den;

  __syncthreads();
  red[t] = v * v;
  __syncthreads();
  for (int s = 256; s > 0; s >>= 1) {
    if (t < s) red[t] += red[t + s];
    __syncthreads();
  }
  const float sqv = red[0];
  const float scv = sqv / ((1.f + sqv) * sqrtf(sqv + 1e-7f));
  out[cap * HDIM + t] = v * scv;
}

// ---------------------------------------------------------------------------
extern "C" void kernel_launch(void* const* d_in, const int* in_sizes, int n_in,
                              void* d_out, int out_size, void* d_ws,
                              size_t ws_size, hipStream_t stream) {
  const float* x = (const float*)d_in[0];     // [131072,512]
  const float* W = (const float*)d_in[1];     // [512,512]
  const float* bias = (const float*)d_in[2];  // [512]
  float* out = (float*)d_out;                 // [64,512]
  char* ws = (char*)d_ws;

  __half* e = (__half*)ws;                            // 134217728 B
  float* u_gemm = (float*)(ws + (size_t)134217728);   // 64*32*512 f
  float* u_a = u_gemm + (size_t)64 * 32 * 512;        // 64*32*512 f
  float* u_b = u_a + (size_t)64 * 32 * 512;           // 64*32*512 f
  float* den_a = u_b + (size_t)64 * 32 * 512;         // 2048 f
  float* den_b = den_a + 2048;                        // 2048 f
  float* b = den_b + 2048;                            // 131072 f
  _Float16* wf = (_Float16*)(b + 131072);             // 262144 h

  prep_w_kernel<<<256, 256, 0, stream>>>(W, wf);
  gemm_kernel<<<2048, 512, 0, stream>>>(x, wf, bias, e, u_gemm);

  // iteration 1's reduction was fused into the GEMM epilogue (b=0 uniform)
  route_iter_kernel<true><<<2048, 256, 0, stream>>>(e, u_gemm, nullptr, b,
                                                    u_a, den_a);
  route_iter_kernel<false><<<2048, 256, 0, stream>>>(e, u_a, den_a, b,
                                                     u_b, den_b);
  route_final_kernel<<<64, 512, 0, stream>>>(u_b, den_b, out);
}

// Round 6
// 628.147 us; speedup vs baseline: 1.0926x; 1.0926x over previous
//
#include <hip/hip_runtime.h>
#include <hip/hip_fp16.h>

// Problem constants: C=64, S=2048, H=512; rows = C*S = 131072
#define HDIM 512

typedef __fp16 fp16x2 __attribute__((ext_vector_type(2)));
typedef _Float16 h8 __attribute__((ext_vector_type(8)));
typedef __attribute__((ext_vector_type(4))) float floatx4;

// raw barrier: LDS-visibility only, no vmem drain (unlike __syncthreads)
__device__ __forceinline__ void lds_barrier() {
  asm volatile("s_waitcnt lgkmcnt(0)\n\ts_barrier" ::: "memory");
}
__device__ __forceinline__ void issue_fence() {  // pin vm-issue order
  asm volatile("" ::: "memory");
}

// ---------------------------------------------------------------------------
// Kernel 1: W fp32 -> fp16 (RTE)
// ---------------------------------------------------------------------------
__global__ __launch_bounds__(256) void prep_w_kernel(
    const float* __restrict__ W, _Float16* __restrict__ wf) {
  int i = (blockIdx.x * 256 + threadIdx.x) * 4;
  float4 f = *(const float4*)(W + i);
  wf[i + 0] = (_Float16)f.x;
  wf[i + 1] = (_Float16)f.y;
  wf[i + 2] = (_Float16)f.z;
  wf[i + 3] = (_Float16)f.w;
}

// ---------------------------------------------------------------------------
// Kernel 2: fused GEMM — round-4-proven (160 us, passed): BM=128 x BN=512,
// BK=32, 8 waves, 4-deep W ring via global_load_lds, dma+x issued before the
// barrier at distance 2. Epilogue: full-row squash + e write + iteration-1
// partial col-sums u_gemm[cap][16][512] (den after iter 1 is exactly 2048).
// ---------------------------------------------------------------------------
#define XS_H (128 * 40)  // x tile, stride padded 32->40 halves
#define WS_H (512 * 32)  // w tile halves per buffer

__device__ __forceinline__ void issue_w_dma(const _Float16* __restrict__ wf,
                                            _Float16* dst, int kt, int tid,
                                            int widx) {
#pragma unroll
  for (int q = 0; q < 4; ++q) {
    int idx = q * 512 + tid;
    int n = idx >> 2;                      // W row (output col), 0..511
    int src = (idx & 3) ^ ((n >> 1) & 3);  // source-side XOR swizzle
    size_t goff = (size_t)n * HDIM + kt * 32 + src * 8;
    __builtin_amdgcn_global_load_lds(
        (const __attribute__((address_space(1))) void*)(wf + goff),
        (__attribute__((address_space(3))) void*)(dst +
                                                  (q * 512 + widx * 64) * 8),
        16, 0, 0);
  }
}

__global__ __launch_bounds__(512, 2) void gemm_kernel(
    const float* __restrict__ x, const _Float16* __restrict__ wf,
    const float* __restrict__ bias, __half* __restrict__ e,
    float* __restrict__ u_gemm) {
  __shared__ __align__(16) _Float16 smem[2 * XS_H + 4 * WS_H];  // 151552 B
  _Float16* xs[2] = {smem, smem + XS_H};
  _Float16* wsm = smem + 2 * XS_H;

  const int tid = threadIdx.x;
  const int lane = tid & 63;
  const int widx = tid >> 6;       // 0..7
  const int wave_m = widx >> 2;    // 0..1
  const int wave_n = widx & 3;     // 0..3
  const int lrow = lane & 15, quad = lane >> 4;

  const int bid = blockIdx.x;      // 1024 blocks, 128 rows each
  const int row0 = bid * 128;

  const int xrow = tid >> 2;       // 0..127
  const int xcg = tid & 3;         // 8-float chunk within 32-float K-tile
  const float* xbase = x + (size_t)(row0 + xrow) * HDIM + xcg * 8;

  floatx4 acc[4][8];
#pragma unroll
  for (int i = 0; i < 4; ++i)
#pragma unroll
    for (int j = 0; j < 8; ++j) acc[i][j] = (floatx4){0.f, 0.f, 0.f, 0.f};

  float4 xr[2][2];

  // prologue: dma_0, x_0, dma_1, x_1 (dma before x => drained by x's wait)
  issue_w_dma(wf, wsm + 0 * WS_H, 0, tid, widx);
  issue_fence();
  xr[0][0] = *(const float4*)xbase;
  xr[0][1] = *(const float4*)(xbase + 4);
  issue_fence();
  issue_w_dma(wf, wsm + 1 * WS_H, 1, tid, widx);
  issue_fence();
  xr[1][0] = *(const float4*)(xbase + 32);
  xr[1][1] = *(const float4*)(xbase + 36);
  issue_fence();

  const int chunkB = quad ^ ((lrow >> 1) & 3);  // read-side swizzle

#pragma unroll
  for (int t = 0; t < 16; ++t) {
    // ---- stage x_t (fp32->fp16); compiler waits x_t here, draining dma_t
    {
      float4 a0 = xr[t & 1][0], a1 = xr[t & 1][1];
      union { h8 v8; fp16x2 v2[4]; } u;
      u.v2[0] = __builtin_amdgcn_cvt_pkrtz(a0.x, a0.y);
      u.v2[1] = __builtin_amdgcn_cvt_pkrtz(a0.z, a0.w);
      u.v2[2] = __builtin_amdgcn_cvt_pkrtz(a1.x, a1.y);
      u.v2[3] = __builtin_amdgcn_cvt_pkrtz(a1.z, a1.w);
      *(h8*)&xs[t & 1][xrow * 40 + xcg * 8] = u.v8;
    }
    // ---- issue next loads BEFORE the barrier (dma older than x)
    if (t <= 13) {
      issue_w_dma(wf, wsm + ((t + 2) & 3) * WS_H, t + 2, tid, widx);
      issue_fence();
      const float* gp = xbase + (t + 2) * 32;
      xr[t & 1][0] = *(const float4*)gp;
      xr[t & 1][1] = *(const float4*)(gp + 4);
      issue_fence();
    }
    lds_barrier();  // xs(t) visible AND all waves' dma_t drained (via stage)
    // ---- compute
    const _Float16* xsr = xs[t & 1];
    const _Float16* wcur = wsm + (t & 3) * WS_H;
    h8 a[4], bh[8];
#pragma unroll
    for (int mt = 0; mt < 4; ++mt)
      a[mt] = *(const h8*)&xsr[(wave_m * 64 + mt * 16 + lrow) * 40 + quad * 8];
#pragma unroll
    for (int nt = 0; nt < 8; ++nt)
      bh[nt] =
          *(const h8*)&wcur[(wave_n * 128 + nt * 16 + lrow) * 32 + chunkB * 8];
    __builtin_amdgcn_s_setprio(1);
#pragma unroll
    for (int mt = 0; mt < 4; ++mt)
#pragma unroll
      for (int nt = 0; nt < 8; ++nt)
        acc[mt][nt] = __builtin_amdgcn_mfma_f32_16x16x32_f16(
            a[mt], bh[nt], acc[mt][nt], 0, 0, 0);
    __builtin_amdgcn_s_setprio(0);
  }

  // ---- epilogue: squash + e-write + iteration-1 partials (no atomics) ----
  float* sqp = (float*)smem;        // [4][128]  (reuses xs[0] region)
  float* scs = (float*)smem + 512;  // [128]
  float* upl = (float*)smem + 640;  // [2][512]

  float bias_v[8];
  int colg[8];
#pragma unroll
  for (int nt = 0; nt < 8; ++nt) {
    colg[nt] = wave_n * 128 + nt * 16 + lrow;
    bias_v[nt] = bias[colg[nt]];
  }
#pragma unroll
  for (int mt = 0; mt < 4; ++mt) {
#pragma unroll
    for (int r = 0; r < 4; ++r) {
      float s = 0.f;
#pragma unroll
      for (int nt = 0; nt < 8; ++nt) {
        float yv = acc[mt][nt][r] + bias_v[nt];
        s += yv * yv;
      }
      s += __shfl_xor(s, 1, 64);
      s += __shfl_xor(s, 2, 64);
      s += __shfl_xor(s, 4, 64);
      s += __shfl_xor(s, 8, 64);
      if (lrow == 0)
        sqp[wave_n * 128 + wave_m * 64 + mt * 16 + quad * 4 + r] = s;
    }
  }
  lds_barrier();
  if (tid < 128) {
    float s = sqp[tid] + sqp[128 + tid] + sqp[256 + tid] + sqp[384 + tid];
    scs[tid] = s / ((1.f + s) * sqrtf(s + 1e-7f));
  }
  lds_barrier();

  float up[8] = {0.f, 0.f, 0.f, 0.f, 0.f, 0.f, 0.f, 0.f};
#pragma unroll
  for (int mt = 0; mt < 4; ++mt) {
#pragma unroll
    for (int r = 0; r < 4; ++r) {
      int row_local = wave_m * 64 + mt * 16 + quad * 4 + r;
      float scv = scs[row_local];
      __half* erow = e + (size_t)(row0 + row_local) * HDIM;
#pragma unroll
      for (int nt = 0; nt < 8; ++nt) {
        float ev = (acc[mt][nt][r] + bias_v[nt]) * scv;
        erow[colg[nt]] = __float2half(ev);
        up[nt] += ev;
      }
    }
  }
#pragma unroll
  for (int nt = 0; nt < 8; ++nt) {
    float v = up[nt];
    v += __shfl_xor(v, 16, 64);
    v += __shfl_xor(v, 32, 64);
    if (quad == 0) upl[wave_m * 512 + colg[nt]] = v;
  }
  lds_barrier();
  // u_gemm[cap][chunk][col]; 16 chunks (128-row blocks) per capsule
  u_gemm[(size_t)(bid >> 4) * 16 * HDIM + (size_t)(bid & 15) * HDIM + tid] =
      upl[tid] + upl[512 + tid];
}

// ---------------------------------------------------------------------------
// Kernel 3: one routing iteration (round-4 geometry: 1024 blocks x 256,
// 32 rows/wave, launch_bounds(256,4) => VGPR cap 128, no spill).
// Two chain fixes vs round 4:
//  (a) b preloaded ONCE per wave (coalesced) and distributed via __shfl —
//      removes 8 serial dependent global loads from the per-group chain;
//  (b) distance-2 e-prefetch via 3-slot register ring (~500-900 cyc load
//      latency vs ~350 cyc compute chain; distance 1 left it exposed).
// ---------------------------------------------------------------------------
template <bool FIRST>
__global__ __launch_bounds__(256, 4) void route_iter_kernel(
    const __half* __restrict__ e, const float* __restrict__ u_in,
    const float* __restrict__ den_in, float* __restrict__ b,
    float* __restrict__ u_out, float* __restrict__ den_out) {
  const int tid = threadIdx.x;
  const int w = tid >> 6;
  const int lane = tid & 63;
  const int bid = blockIdx.x;
  const int cap = bid >> 4;  // 16 blocks per capsule
  const int r0 = bid * 128;

  __shared__ float csh[512];
  __shared__ float red[256];
  __shared__ float lred[4][512];
  __shared__ float ldn[4];
  __shared__ float sden;

  // ---- phase R: c = squash(sum u / den) for this block's capsule ----
  float v0 = 0.f, v1 = 0.f;
  {
    const float* upb = u_in + (size_t)cap * 16 * HDIM;
#pragma unroll
    for (int ch = 0; ch < 16; ++ch) {
      v0 += upb[ch * HDIM + tid];
      v1 += upb[ch * HDIM + tid + 256];
    }
  }
  float den;
  if (FIRST) {
    den = 2048.f;  // sum of exp(0) over S, exactly
  } else {
    red[tid] = (tid < 16) ? den_in[cap * 16 + tid] : 0.f;
    __syncthreads();
    if (tid == 0) {
      float s = 0.f;
#pragma unroll
      for (int i = 0; i < 16; ++i) s += red[i];
      sden = s;
    }
    __syncthreads();
    den = sden;
    __syncthreads();
  }
  v0 /= den;
  v1 /= den;
  red[tid] = v0 * v0 + v1 * v1;
  __syncthreads();
  for (int s = 128; s > 0; s >>= 1) {
    if (tid < s) red[tid] += red[tid + s];
    __syncthreads();
  }
  const float sqv = red[0];
  const float scv = sqv / ((1.f + sqv) * sqrtf(sqv + 1e-7f));
  csh[tid] = v0 * scv;
  csh[tid + 256] = v1 * scv;
  __syncthreads();

  // ---- phase B: b += e.c ; partial softmax-weighted sums ----
  float c8[8];
#pragma unroll
  for (int k = 0; k < 8; ++k) c8[k] = csh[lane * 8 + k];
  // (a) preload this wave's 32 b values once (coalesced, off critical path)
  float bline = 0.f;
  if (!FIRST) bline = b[r0 + w * 32 + (lane & 31)];
  float u8[8] = {0, 0, 0, 0, 0, 0, 0, 0};
  float den_w = 0.f;

  union U { int4 v; __half hh[8]; };
  U buf[3][4];
  const __half* yb = e + (size_t)(r0 + w * 32) * HDIM + lane * 8;
#pragma unroll
  for (int j = 0; j < 4; ++j) buf[0][j].v = *(const int4*)(yb + (size_t)j * HDIM);
  issue_fence();
#pragma unroll
  for (int j = 0; j < 4; ++j)
    buf[1][j].v = *(const int4*)(yb + (size_t)(4 + j) * HDIM);
  issue_fence();

#pragma unroll
  for (int g = 0; g < 8; ++g) {
    const int rg = r0 + w * 32 + g * 4;
    // (b) distance-2 prefetch
    if (g < 6) {
#pragma unroll
      for (int j = 0; j < 4; ++j)
        buf[(g + 2) % 3][j].v =
            *(const int4*)(yb + (size_t)(g * 4 + 8 + j) * HDIM);
      issue_fence();
    }
    const U* cur = buf[g % 3];
    float dot[4];
#pragma unroll
    for (int j = 0; j < 4; ++j) {
      float d = 0.f;
#pragma unroll
      for (int k = 0; k < 8; ++k) d += __half2float(cur[j].hh[k]) * c8[k];
      dot[j] = d;
    }
#pragma unroll
    for (int s = 1; s < 64; s <<= 1) {
#pragma unroll
      for (int j = 0; j < 4; ++j) dot[j] += __shfl_xor(dot[j], s, 64);
    }
#pragma unroll
    for (int j = 0; j < 4; ++j) {
      float bn = FIRST ? dot[j] : (__shfl(bline, g * 4 + j, 64) + dot[j]);
      if (FIRST && lane == 0) b[rg + j] = bn;  // launch-2 write is dead
      float wj = __expf(bn);  // |b| small: no max-subtraction needed
      den_w += wj;
#pragma unroll
      for (int k = 0; k < 8; ++k) u8[k] += wj * __half2float(cur[j].hh[k]);
    }
  }

  // intra-block reduction: 4 waves -> one partial per block
#pragma unroll
  for (int k = 0; k < 8; ++k) lred[w][lane * 8 + k] = u8[k];
  if (lane == 0) ldn[w] = den_w;
  __syncthreads();
  float* ur = u_out + (size_t)cap * 16 * HDIM + (size_t)(bid & 15) * HDIM;
#pragma unroll
  for (int hh = 0; hh < 2; ++hh) {
    int h = hh * 256 + tid;
    ur[h] = lred[0][h] + lred[1][h] + lred[2][h] + lred[3][h];
  }
  if (tid == 0)
    den_out[cap * 16 + (bid & 15)] = ldn[0] + ldn[1] + ldn[2] + ldn[3];
}

// ---------------------------------------------------------------------------
// Kernel 4: final phase R only: c3 = squash(sum u / sum den) -> out
// ---------------------------------------------------------------------------
__global__ __launch_bounds__(512) void route_final_kernel(
    const float* __restrict__ u_in, const float* __restrict__ den_in,
    float* __restrict__ out) {
  const int cap = blockIdx.x;
  const int t = threadIdx.x;
  __shared__ float red[512];
  __shared__ float sden;

  red[t] = (t < 16) ? den_in[cap * 16 + t] : 0.f;
  __syncthreads();
  if (t == 0) {
    float s = 0.f;
#pragma unroll
    for (int i = 0; i < 16; ++i) s += red[i];
    sden = s;
  }
  __syncthreads();
  const float den = sden;

  float v = 0.f;
  const float* up = u_in + (size_t)cap * 16 * HDIM + t;
#pragma unroll
  for (int ch = 0; ch < 16; ++ch) v += up[ch * HDIM];
  v /= den;

  __syncthreads();
  red[t] = v * v;
  __syncthreads();
  for (int s = 256; s > 0; s >>= 1) {
    if (t < s) red[t] += red[t + s];
    __syncthreads();
  }
  const float sqv = red[0];
  const float scv = sqv / ((1.f + sqv) * sqrtf(sqv + 1e-7f));
  out[cap * HDIM + t] = v * scv;
}

// ---------------------------------------------------------------------------
extern "C" void kernel_launch(void* const* d_in, const int* in_sizes, int n_in,
                              void* d_out, int out_size, void* d_ws,
                              size_t ws_size, hipStream_t stream) {
  const float* x = (const float*)d_in[0];     // [131072,512]
  const float* W = (const float*)d_in[1];     // [512,512]
  const float* bias = (const float*)d_in[2];  // [512]
  float* out = (float*)d_out;                 // [64,512]
  char* ws = (char*)d_ws;

  __half* e = (__half*)ws;                            // 134217728 B
  float* u_gemm = (float*)(ws + (size_t)134217728);   // 64*16*512 f
  float* u_a = u_gemm + (size_t)64 * 16 * 512;        // 64*16*512 f
  float* u_b = u_a + (size_t)64 * 16 * 512;           // 64*16*512 f
  float* den_a = u_b + (size_t)64 * 16 * 512;         // 1024 f
  float* den_b = den_a + 1024;                        // 1024 f
  float* b = den_b + 1024;                            // 131072 f
  _Float16* wf = (_Float16*)(b + 131072);             // 262144 h

  prep_w_kernel<<<256, 256, 0, stream>>>(W, wf);
  gemm_kernel<<<1024, 512, 0, stream>>>(x, wf, bias, e, u_gemm);

  // iteration 1's reduction was fused into the GEMM epilogue (b=0 uniform)
  route_iter_kernel<true><<<1024, 256, 0, stream>>>(e, u_gemm, nullptr, b,
                                                    u_a, den_a);
  route_iter_kernel<false><<<1024, 256, 0, stream>>>(e, u_a, den_a, b,
                                                     u_b, den_b);
  route_final_kernel<<<64, 512, 0, stream>>>(u_b, den_b, out);
}